// Round 14
// baseline (913.366 us; speedup 1.0000x reference)
//
#include <hip/hip_runtime.h>

static constexpr int NN = 16384;
static constexpr int NE = 262144;   // 2^18

#define DEV __device__ __forceinline__

typedef float v2f __attribute__((ext_vector_type(2)));

DEV float sus(float x) { return x > 0.0f ? __expf(-1.0f / x) : 0.0f; }

DEV unsigned fkey(float f) {
    unsigned b = __float_as_uint(f);
    return b ^ ((b >> 31) ? 0xFFFFFFFFu : 0x80000000u);
}
DEV float funkey(unsigned k) {
    unsigned b = (k >> 31) ? (k ^ 0x80000000u) : ~k;
    return __uint_as_float(b);
}

static constexpr float INV_SQRT20 = 0.22360679774997896f;
static constexpr float INV_SQRT8  = 0.35355339059327373f;
static constexpr float INV3       = 0.5773502691896258f;   // 1/sqrt(3)
static constexpr float NORM_TP    = 0.20412414523193154f;  // 1/sqrt(24)
static constexpr float FAN        = 0.11180339887498948f;  // 1/sqrt(80)
static constexpr float SQRT3      = 1.7320508075688772f;
static constexpr float S0C        = INV_SQRT20 * NORM_TP;
static constexpr float S1C        = INV_SQRT20 * NORM_TP * INV3;

struct alignas(16) F40 { float v[40]; };

// ---------------------------------------------------------------------------
// K0: per-node precompute. qd (q through Wd), self-interaction -> out,
//     z=0, gmax=0.
// ---------------------------------------------------------------------------
__global__ __launch_bounds__(256) void node_pre_kernel(
    const float* __restrict__ f_in,
    const float* __restrict__ Wq0, const float* __restrict__ Wq1,
    const float* __restrict__ Wd0, const float* __restrict__ Wd1,
    const float* __restrict__ Ws0, const float* __restrict__ Ws1,
    float* __restrict__ qd, float* __restrict__ z,
    unsigned* __restrict__ gmax, float* __restrict__ out)
{
    int n = blockIdx.x * 256 + threadIdx.x;
    if (n >= NN) return;

    F40 fr = *(const F40*)(f_in + (size_t)n * 40);
    float f0[16], f1[8][3];
#pragma unroll
    for (int i = 0; i < 16; ++i) f0[i] = fr.v[i];
#pragma unroll
    for (int i = 0; i < 8; ++i)
#pragma unroll
        for (int c = 0; c < 3; ++c) f1[i][c] = fr.v[16 + i * 3 + c];

    float q0[8];
#pragma unroll
    for (int o = 0; o < 8; ++o) {
        float a = 0.f;
#pragma unroll
        for (int i = 0; i < 16; ++i) a += f0[i] * Wq0[i * 8 + o];
        q0[o] = a * 0.25f;
    }
#pragma unroll
    for (int j = 0; j < 8; ++j) {
        float a = 0.f;
#pragma unroll
        for (int o = 0; o < 8; ++o) a += q0[o] * Wd0[o * 8 + j];
        qd[n * 20 + j] = a;
    }
    float q1[4][3];
#pragma unroll
    for (int o = 0; o < 4; ++o)
#pragma unroll
        for (int c = 0; c < 3; ++c) {
            float a = 0.f;
#pragma unroll
            for (int i = 0; i < 8; ++i) a += f1[i][c] * Wq1[i * 4 + o];
            q1[o][c] = a * INV_SQRT8;
        }
#pragma unroll
    for (int j = 0; j < 4; ++j)
#pragma unroll
        for (int c = 0; c < 3; ++c) {
            float a = 0.f;
#pragma unroll
            for (int o = 0; o < 4; ++o) a += q1[o][c] * Wd1[o * 4 + j];
            qd[n * 20 + 8 + j * 3 + c] = a;
        }

    // self interaction -> out (we own the init of d_out)
#pragma unroll
    for (int o = 0; o < 16; ++o) {
        float a = 0.f;
#pragma unroll
        for (int i = 0; i < 16; ++i) a += f0[i] * Ws0[i * 16 + o];
        out[(size_t)n * 40 + o] = a * 0.25f;
    }
#pragma unroll
    for (int o = 0; o < 8; ++o)
#pragma unroll
        for (int c = 0; c < 3; ++c) {
            float a = 0.f;
#pragma unroll
            for (int i = 0; i < 8; ++i) a += f1[i][c] * Ws1[i * 8 + o];
            out[(size_t)n * 40 + 16 + o * 3 + c] = a * INV_SQRT8;
        }

    z[n] = 0.0f;
    if (n == 0) *gmax = 0u;
}

// ---------------------------------------------------------------------------
// K1: per-edge K tensor product + logit (+ block max -> gmax).
//     Packed-f32 (v2f) inner loops over adjacent output pairs.
// ---------------------------------------------------------------------------
__global__ __launch_bounds__(256) void edge_k_kernel(
    const float* __restrict__ pos, const float* __restrict__ f_in,
    const int* __restrict__ esrc, const int* __restrict__ edst,
    const float* __restrict__ Wk1, const float* __restrict__ Wk2,
    const float* __restrict__ qd,
    float* __restrict__ logitbuf, float* __restrict__ cutoffbuf,
    unsigned* __restrict__ gmax)
{
    int e = blockIdx.x * 256 + threadIdx.x;
    int src = esrc[e], dst = edst[e];

    float px = pos[dst * 3 + 0] - pos[src * 3 + 0];
    float py = pos[dst * 3 + 1] - pos[src * 3 + 1];
    float pz = pos[dst * 3 + 2] - pos[src * 3 + 2];
    float len = sqrtf(px * px + py * py + pz * pz);
    float inv = SQRT3 / fmaxf(len, 1e-9f);
    float shx = px * inv, shy = py * inv, shz = pz * inv;
    cutoffbuf[e] = sus(10.0f - len);
    float emb[20];
    const float cemb = (float)(1.14136 * 7.3890560989306495 * 4.47213595499958);
#pragma unroll
    for (int b = 0; b < 20; ++b) {
        float d = (len - (float)(b + 1) * (10.0f / 21.0f)) * 2.1f;
        emb[b] = cemb * sus(d + 1.0f) * sus(1.0f - d);
    }

    F40 fr = *(const F40*)(f_in + (size_t)src * 40);
    float f0[16], f1[8][3], dv[8];
#pragma unroll
    for (int i = 0; i < 16; ++i) f0[i] = fr.v[i];
#pragma unroll
    for (int i = 0; i < 8; ++i) {
        float a = fr.v[16 + i * 3 + 0];
        float b = fr.v[16 + i * 3 + 1];
        float c = fr.v[16 + i * 3 + 2];
        f1[i][0] = a; f1[i][1] = b; f1[i][2] = c;
        dv[i] = (a * shx + b * shy + c * shz) * INV3;
    }

    v2f k0a2[4] = {}, Aa2[2] = {}, Ba2[2][3] = {};
#pragma clang loop unroll(disable)
    for (int h = 0; h < 20; ++h) {
        float a = 0.f;
#pragma unroll
        for (int b = 0; b < 20; ++b) a += emb[b] * Wk1[b * 20 + h];
        float hk = fmaxf(a * INV_SQRT20, 0.0f);
        const float* wr = Wk2 + h * 288;
#pragma unroll
        for (int p = 0; p < 4; ++p) {
            v2f s = {0.f, 0.f};
#pragma unroll
            for (int i = 0; i < 16; ++i)
                s += f0[i] * *(const v2f*)(wr + i * 8 + 2 * p);
#pragma unroll
            for (int i = 0; i < 8; ++i)
                s += dv[i] * *(const v2f*)(wr + 128 + i * 8 + 2 * p);
            k0a2[p] += hk * s;
        }
#pragma unroll
        for (int p = 0; p < 2; ++p) {
            v2f s = {0.f, 0.f};
#pragma unroll
            for (int i = 0; i < 16; ++i)
                s += f0[i] * *(const v2f*)(wr + 192 + i * 4 + 2 * p);
            Aa2[p] += hk * s;
            v2f s0 = {0.f, 0.f}, s1 = {0.f, 0.f}, s2 = {0.f, 0.f};
#pragma unroll
            for (int i = 0; i < 8; ++i) {
                v2f w2 = *(const v2f*)(wr + 256 + i * 4 + 2 * p);
                s0 += f1[i][0] * w2; s1 += f1[i][1] * w2; s2 += f1[i][2] * w2;
            }
            Ba2[p][0] += hk * s0; Ba2[p][1] += hk * s1; Ba2[p][2] += hk * s2;
        }
    }

    const float* qdd = qd + (size_t)dst * 20;
    float lg = 0.f;
#pragma unroll
    for (int p = 0; p < 4; ++p)
        lg += qdd[2 * p] * (k0a2[p].x * S0C) + qdd[2 * p + 1] * (k0a2[p].y * S0C);
    float lg1 = 0.f;
#pragma unroll
    for (int p = 0; p < 2; ++p) {
        float kx = (Aa2[p].x * shx + Ba2[p][0].x) * S1C;
        float ky = (Aa2[p].x * shy + Ba2[p][1].x) * S1C;
        float kz = (Aa2[p].x * shz + Ba2[p][2].x) * S1C;
        lg1 += qdd[8 + 6 * p + 0] * kx + qdd[8 + 6 * p + 1] * ky + qdd[8 + 6 * p + 2] * kz;
        kx = (Aa2[p].y * shx + Ba2[p][0].y) * S1C;
        ky = (Aa2[p].y * shy + Ba2[p][1].y) * S1C;
        kz = (Aa2[p].y * shz + Ba2[p][2].y) * S1C;
        lg1 += qdd[8 + 6 * p + 3] * kx + qdd[8 + 6 * p + 4] * ky + qdd[8 + 6 * p + 5] * kz;
    }
    lg = (lg + lg1 * INV3) * FAN;
    logitbuf[e] = lg;

    float m = lg;
#pragma unroll
    for (int off = 32; off >= 1; off >>= 1) m = fmaxf(m, __shfl_xor(m, off, 64));
    __shared__ float sm[4];
    int lane = threadIdx.x & 63, wid = threadIdx.x >> 6;
    if (lane == 0) sm[wid] = m;
    __syncthreads();
    if (threadIdx.x == 0) {
        float mm = fmaxf(fmaxf(sm[0], sm[1]), fmaxf(sm[2], sm[3]));
        atomicMax(gmax, fkey(mm));
    }
}

// ---------------------------------------------------------------------------
// K2: per-edge V tensor product -> vws SoA [40][NE] (coalesced, by edge id).
//     Packed-f32 inner loops.
// ---------------------------------------------------------------------------
__global__ __launch_bounds__(256) void edge_v_kernel(
    const float* __restrict__ pos, const float* __restrict__ f_in,
    const int* __restrict__ esrc, const int* __restrict__ edst,
    const float* __restrict__ Wv1, const float* __restrict__ Wv2,
    float* __restrict__ vws)
{
    int e = blockIdx.x * 256 + threadIdx.x;
    int src = esrc[e], dst = edst[e];

    float px = pos[dst * 3 + 0] - pos[src * 3 + 0];
    float py = pos[dst * 3 + 1] - pos[src * 3 + 1];
    float pz = pos[dst * 3 + 2] - pos[src * 3 + 2];
    float len = sqrtf(px * px + py * py + pz * pz);
    float inv = SQRT3 / fmaxf(len, 1e-9f);
    float shx = px * inv, shy = py * inv, shz = pz * inv;
    float emb[20];
    const float cemb = (float)(1.14136 * 7.3890560989306495 * 4.47213595499958);
#pragma unroll
    for (int b = 0; b < 20; ++b) {
        float d = (len - (float)(b + 1) * (10.0f / 21.0f)) * 2.1f;
        emb[b] = cemb * sus(d + 1.0f) * sus(1.0f - d);
    }

    F40 fr = *(const F40*)(f_in + (size_t)src * 40);
    float f0[16], f1[8][3], dv[8];
#pragma unroll
    for (int i = 0; i < 16; ++i) f0[i] = fr.v[i];
#pragma unroll
    for (int i = 0; i < 8; ++i) {
        float a = fr.v[16 + i * 3 + 0];
        float b = fr.v[16 + i * 3 + 1];
        float c = fr.v[16 + i * 3 + 2];
        f1[i][0] = a; f1[i][1] = b; f1[i][2] = c;
        dv[i] = (a * shx + b * shy + c * shz) * INV3;
    }

    v2f v0a2[8] = {}, Aa2[4] = {}, Ba2[4][3] = {};
#pragma clang loop unroll(disable)
    for (int h = 0; h < 20; ++h) {
        float a = 0.f;
#pragma unroll
        for (int b = 0; b < 20; ++b) a += emb[b] * Wv1[b * 20 + h];
        float hv = fmaxf(a * INV_SQRT20, 0.0f);
        const float* wr = Wv2 + h * 576;
#pragma unroll
        for (int p = 0; p < 8; ++p) {
            v2f s = {0.f, 0.f};
#pragma unroll
            for (int i = 0; i < 16; ++i)
                s += f0[i] * *(const v2f*)(wr + i * 16 + 2 * p);
#pragma unroll
            for (int i = 0; i < 8; ++i)
                s += dv[i] * *(const v2f*)(wr + 256 + i * 16 + 2 * p);
            v0a2[p] += hv * s;
        }
#pragma unroll
        for (int p = 0; p < 4; ++p) {
            v2f s = {0.f, 0.f};
#pragma unroll
            for (int i = 0; i < 16; ++i)
                s += f0[i] * *(const v2f*)(wr + 384 + i * 8 + 2 * p);
            Aa2[p] += hv * s;
            v2f s0 = {0.f, 0.f}, s1 = {0.f, 0.f}, s2 = {0.f, 0.f};
#pragma unroll
            for (int i = 0; i < 8; ++i) {
                v2f w2 = *(const v2f*)(wr + 512 + i * 8 + 2 * p);
                s0 += f1[i][0] * w2; s1 += f1[i][1] * w2; s2 += f1[i][2] * w2;
            }
            Ba2[p][0] += hv * s0; Ba2[p][1] += hv * s1; Ba2[p][2] += hv * s2;
        }
    }

#pragma unroll
    for (int p = 0; p < 8; ++p) {
        vws[(size_t)(2 * p) * NE + e]     = v0a2[p].x * S0C;
        vws[(size_t)(2 * p + 1) * NE + e] = v0a2[p].y * S0C;
    }
#pragma unroll
    for (int p = 0; p < 4; ++p) {
        int o0 = 2 * p, o1 = 2 * p + 1;
        vws[(size_t)(16 + o0 * 3 + 0) * NE + e] = (Aa2[p].x * shx + Ba2[p][0].x) * S1C;
        vws[(size_t)(16 + o0 * 3 + 1) * NE + e] = (Aa2[p].x * shy + Ba2[p][1].x) * S1C;
        vws[(size_t)(16 + o0 * 3 + 2) * NE + e] = (Aa2[p].x * shz + Ba2[p][2].x) * S1C;
        vws[(size_t)(16 + o1 * 3 + 0) * NE + e] = (Aa2[p].y * shx + Ba2[p][0].y) * S1C;
        vws[(size_t)(16 + o1 * 3 + 1) * NE + e] = (Aa2[p].y * shy + Ba2[p][1].y) * S1C;
        vws[(size_t)(16 + o1 * 3 + 2) * NE + e] = (Aa2[p].y * shz + Ba2[p][2].y) * S1C;
    }
}

// ---------------------------------------------------------------------------
// K3: ex = cutoff * exp(logit - max); z[dst] += ex
// ---------------------------------------------------------------------------
__global__ __launch_bounds__(256) void edge_exp_kernel(
    const int* __restrict__ edst,
    const float* __restrict__ logitbuf, const float* __restrict__ cutoffbuf,
    const unsigned* __restrict__ gmax,
    float* __restrict__ exbuf, float* __restrict__ z)
{
    int e = blockIdx.x * 256 + threadIdx.x;
    float gm = funkey(*gmax);
    float ex = cutoffbuf[e] * __expf(logitbuf[e] - gm);
    exbuf[e] = ex;
    atomicAdd(&z[edst[e]], ex);
}

// ---------------------------------------------------------------------------
// K4: scatter with inline attention weight.  One thread per (t,e).
//     out[dst, t] += sqrt(ex/z~ + eps) * v[t][e]
// ---------------------------------------------------------------------------
__global__ __launch_bounds__(256) void scatter_kernel(
    const int* __restrict__ edst,
    const float* __restrict__ exbuf, const float* __restrict__ z,
    const float* __restrict__ vws, float* __restrict__ out)
{
    unsigned tid = blockIdx.x * 256 + threadIdx.x;
    unsigned e = tid & (NE - 1);
    unsigned t = tid >> 18;
    int d = edst[e];
    float zz = z[d];
    zz = (zz < 1e-6f) ? 1.0f : zz;
    float w = sqrtf(exbuf[e] / zz + 1e-6f);
    atomicAdd(&out[(size_t)d * 40 + t], w * vws[(size_t)t * NE + e]);
}

// ---------------------------------------------------------------------------
extern "C" void kernel_launch(void* const* d_in, const int* in_sizes, int n_in,
                              void* d_out, int out_size, void* d_ws, size_t ws_size,
                              hipStream_t stream)
{
    const float* pos  = (const float*)d_in[0];
    const float* f_in = (const float*)d_in[1];
    const int*   esrc = (const int*)d_in[2];
    const int*   edst = (const int*)d_in[3];
    const float* Wq0  = (const float*)d_in[4];
    const float* Wq1  = (const float*)d_in[5];
    const float* Wk1  = (const float*)d_in[6];
    const float* Wk2  = (const float*)d_in[7];
    const float* Wv1  = (const float*)d_in[8];
    const float* Wv2  = (const float*)d_in[9];
    const float* Wd0  = (const float*)d_in[10];
    const float* Wd1  = (const float*)d_in[11];
    const float* Ws0  = (const float*)d_in[12];
    const float* Ws1  = (const float*)d_in[13];
    float* out = (float*)d_out;

    float* ws = (float*)d_ws;
    float* qd     = ws;                    // NN*20
    float* logitb = qd + (size_t)NN * 20;  // NE
    float* cutb   = logitb + NE;           // NE
    float* exb    = cutb + NE;             // NE
    float* z      = exb + NE;              // NN
    unsigned* gmax = (unsigned*)(z + NN);  // 1 (+3 pad)
    float* vws    = (float*)(gmax + 4);    // 40*NE SoA by edge id

    node_pre_kernel<<<NN / 256, 256, 0, stream>>>(f_in, Wq0, Wq1, Wd0, Wd1, Ws0, Ws1,
                                                  qd, z, gmax, out);
    edge_k_kernel<<<NE / 256, 256, 0, stream>>>(pos, f_in, esrc, edst, Wk1, Wk2, qd,
                                                logitb, cutb, gmax);
    edge_v_kernel<<<NE / 256, 256, 0, stream>>>(pos, f_in, esrc, edst, Wv1, Wv2, vws);
    edge_exp_kernel<<<NE / 256, 256, 0, stream>>>(edst, logitb, cutb, gmax, exb, z);
    scatter_kernel<<<40 * NE / 256, 256, 0, stream>>>(edst, exb, z, vws, out);
}